// Round 7
// baseline (225.871 us; speedup 1.0000x reference)
//
#include <hip/hip_runtime.h>
#include <hip/hip_bf16.h>
#include <math.h>

// Problem constants
#define T_STEPS 100
#define H_DIM   50
#define Z_DIM   10
#define OUT_DIM 65   // Z + Z*(Z+1)/2 = 10 + 55
#define KP      25   // f16 pairs per gate column
#define NDW     4    // dense waves
#define NWAVES  7    // 3 gru + 4 dense
#define NTHREADS (NWAVES * 64)
#define NIV     105  // intervals: last dense phase (s=99, B2) at iv=104

typedef _Float16 half2v __attribute__((ext_vector_type(2)));

// ---- cross-lane primitives ----
__device__ __forceinline__ float bcast_lane(float v, int lane) {
    return __uint_as_float(__builtin_amdgcn_readlane(__float_as_uint(v), lane));
}
__device__ __forceinline__ unsigned readlane_u(unsigned v, int lane) {
    return (unsigned)__builtin_amdgcn_readlane((int)v, lane);
}
template<int CTRL>
__device__ __forceinline__ float dpp_mov(float x) {
    return __uint_as_float((unsigned)__builtin_amdgcn_update_dpp(
        0, (int)__float_as_uint(x), CTRL, 0xF, 0xF, true));
}
#define DPP_ROW_SHL1 0x101
#define DPP_SHR1     0x111
#define DPP_SHR2     0x112
#define DPP_SHR4     0x114
#define DPP_SHR8     0x118
#define DPP_BCAST15  0x142
#define DPP_BCAST31  0x143

// ---- packed f16 helpers ----
__device__ __forceinline__ unsigned pack_h2(float lo, float hi) {
#if __has_builtin(__builtin_amdgcn_cvt_pkrtz)
    return __builtin_bit_cast(unsigned, __builtin_amdgcn_cvt_pkrtz(lo, hi));
#else
    half2v p; p.x = (_Float16)lo; p.y = (_Float16)hi;
    return __builtin_bit_cast(unsigned, p);
#endif
}
__device__ __forceinline__ float fdot2h(unsigned a, unsigned b, float c) {
#if __has_builtin(__builtin_amdgcn_fdot2)
    return __builtin_amdgcn_fdot2(__builtin_bit_cast(half2v, a),
                                  __builtin_bit_cast(half2v, b), c, false);
#else
    const half2v x = __builtin_bit_cast(half2v, a);
    const half2v y = __builtin_bit_cast(half2v, b);
    return fmaf((float)x.x, (float)y.x, fmaf((float)x.y, (float)y.y, c));
#endif
}

// ---- fast math ----
__device__ __forceinline__ float fast_rcp(float x) { return __builtin_amdgcn_rcpf(x); }
__device__ __forceinline__ float fast_rsq(float x) { return __builtin_amdgcn_rsqf(x); }
__device__ __forceinline__ float fast_sigmoid(float x) {
    return fast_rcp(1.0f + __expf(-x));
}
__device__ __forceinline__ float fast_tanh(float y) {
    return 1.0f - 2.0f * fast_rcp(__expf(2.0f * y) + 1.0f);
}

__device__ __forceinline__ void lds_fence_wave() {
    asm volatile("s_waitcnt lgkmcnt(0)" ::: "memory");
}

// =====================================================================
// ONE dispatch. 7 waves, one unconditional barrier per interval
// (identical count in every wave -> no hang possible).
//   waves 0-2 : r5's proven 3-wave gru recurrence, verbatim math.
//               Interval iv: combine(iv-1) -> matvec(iv). LDS-only.
//   waves 3-6 : dense+nat, step s = (wave-3) mod 4, 4 phases/step,
//               one phase per interval starting at iv = s+2 (hist[s]
//               is published by the barrier at end of interval s+1).
//               W_dense lives in LDS (transposed, preloaded), outputs
//               go to an LDS mirror -> ZERO global ops in the loop ->
//               barrier vmcnt drains are trivial (the r2 failure mode
//               is structurally removed).
// Final: cooperative float4 dump of the 88 KB mirror to `out`.
// =====================================================================
__global__ __launch_bounds__(NTHREADS, 1)
void gru_fused_kernel(
    const float* __restrict__ carry_init,
    const float* __restrict__ W_hr, const float* __restrict__ b_hr,
    const float* __restrict__ s_r,  const float* __restrict__ o_r,
    const float* __restrict__ W_hz, const float* __restrict__ b_hz,
    const float* __restrict__ s_z,  const float* __restrict__ o_z,
    const float* __restrict__ W_hn, const float* __restrict__ b_hn,
    const float* __restrict__ s_n,  const float* __restrict__ o_n,
    const float* __restrict__ W_dense, const float* __restrict__ b_dense,
    float* __restrict__ out)
{
    const int tid  = threadIdx.x;
    const int wave = tid >> 6;
    const int j    = tid & 63;
    const bool isg = (wave < 3);

    __shared__ __align__(16) float hist[T_STEPS][64];   // h history
    __shared__ float gbuf[2][3][64];                    // gate exchange (dbuf)
    __shared__ float WdT[OUT_DIM * 57];                 // W_dense^T, row stride 57
    __shared__ __align__(16) float omir[22000];         // out mirror (88 KB)
    __shared__ __align__(16) float Lp[NDW][56];
    __shared__ float Li[NDW][56];
    __shared__ float Jsh[NDW][100];
    __shared__ float mrow[NDW][12];

    // ---------------- per-path init (pre-loop == "interval 0" work) ----
    // gru state
    unsigned w[KP];
    float bj = 0.0f, sc = 0.0f, of = 0.0f, h = 0.0f;
    float hsl = 0.0f; unsigned hpk = 0;
    // dense state
    int   dwi = 0, col = 0, a = 0, b = 0;
    bool  isd = false;
    float bdp = 0.0f, bd9 = 0.0f, acc = 0.0f, acc9 = 0.0f;

    const float invH = 1.0f / (float)H_DIM;

    if (isg) {
        const bool valid = (j < H_DIM);
        const int  jc    = valid ? j : 0;
        const float* Wg = (wave == 0) ? W_hr : (wave == 1) ? W_hz : W_hn;
        const float* bg = (wave == 0) ? b_hr : (wave == 1) ? b_hz : b_hn;
        const float* sg = (wave == 0) ? s_r  : (wave == 1) ? s_z  : s_n;
        const float* og = (wave == 0) ? o_r  : (wave == 1) ? o_z  : o_n;

        #pragma unroll
        for (int k = 0; k < KP; ++k) {
            const int i0 = 2 * k, i1 = 2 * k + 1;
            w[k] = pack_h2(valid ? Wg[i0 * H_DIM + j] : 0.0f,
                           valid ? Wg[i1 * H_DIM + j] : 0.0f);
        }
        #pragma unroll
        for (int k = 0; k < KP; ++k) asm volatile("" : "+v"(w[k]));

        bj = valid ? bg[jc] : 0.0f;
        sc = sg[jc];
        of = og[jc];
        h  = valid ? carry_init[jc] : 0.0f;
        hsl = dpp_mov<DPP_ROW_SHL1>(h);
        hpk = pack_h2(h, hsl);
        __builtin_amdgcn_s_setprio(1);       // recurrence is the critical path
    } else {
        dwi = wave - 3;
        #pragma unroll
        for (int x = 1; x < Z_DIM; ++x)
            if (j >= x * (x + 1) / 2) a = x;
        b   = j - a * (a + 1) / 2;
        col = (j < 55) ? (10 + j) : (j - 55);
        bdp = b_dense[col];
        bd9 = (j == 0) ? b_dense[9] : 0.0f;
        isd = (j==0)|(j==2)|(j==5)|(j==9)|(j==14)|
              (j==20)|(j==27)|(j==35)|(j==44)|(j==54);
        // Preload W_dense^T into LDS: global read is coalesced (linear),
        // ds_write scattered. One-time; drains at the first barrier.
        const int dtid = dwi * 64 + j;
        for (int idx = dtid; idx < H_DIM * OUT_DIM; idx += NDW * 64) {
            const int i = idx / OUT_DIM, c = idx % OUT_DIM;
            WdT[c * 57 + i] = W_dense[idx];
        }
    }

    // ---------------- the shared interval loop --------------------------
    #pragma unroll 1
    for (int iv = 0; iv < NIV; ++iv) {
        if (isg) {
            if (iv >= 1 && iv <= T_STEPS) {
                // combine step iv-1 (r5 verbatim)
                const int tb = (iv - 1) & 1;
                const float r  = gbuf[tb][0][j];
                const float z  = gbuf[tb][1][j];
                const float gn = gbuf[tb][2][j];
                const float n  = fast_tanh(r * gn);
                h = n + z * (h - n);                 // (1-z)*n + z*h
                if (wave == 0) hist[iv - 1][j] = h;
                hsl = dpp_mov<DPP_ROW_SHL1>(h);
                hpk = pack_h2(h, hsl);
            }
            if (iv < T_STEPS) {
                // hoisted broadcasts (r5's proven hazard fix)
                unsigned hs[KP];
                #pragma unroll
                for (int k = 0; k < KP; ++k) hs[k] = readlane_u(hpk, 2 * k);
                #pragma unroll
                for (int k = 0; k < KP; ++k) asm volatile("" : "+s"(hs[k]));

                float a0 = bj, a1 = 0.0f;
                #pragma unroll
                for (int k = 0; k < KP; k += 2) {
                    a0 = fdot2h(hs[k], w[k], a0);
                    if (k + 1 < KP) a1 = fdot2h(hs[k + 1], w[k + 1], a1);
                }
                const float av = a0 + a1;

                float m = av, q = av * av;
                #define STAGE(C) m += dpp_mov<C>(m); q += dpp_mov<C>(q);
                STAGE(DPP_SHR1) STAGE(DPP_SHR2) STAGE(DPP_SHR4)
                STAGE(DPP_SHR8) STAGE(DPP_BCAST15) STAGE(DPP_BCAST31)
                #undef STAGE
                m = bcast_lane(m, 63); q = bcast_lane(q, 63);

                const float mu  = m * invH;
                const float var = fmaxf(q * invH - mu * mu, 0.0f);
                const float g   = (av - mu) * fast_rsq(var + 1e-6f) * sc + of;
                const float val = (wave == 2) ? g : fast_sigmoid(g);
                gbuf[iv & 1][wave][j] = val;
            }
        } else {
            const int d = iv - 2 - dwi;
            if (d >= 0) {
                const int p = d & 3;            // phase 0..3
                const int s = iv - 2 - p;       // step (s ≡ dwi mod 4)
                if (s < T_STEPS) {
                    if (p == 0) {
                        // ---- A1: matvec k = 0..27 (order = r3's chain) ----
                        acc = bdp; acc9 = bd9;
                        const float4* h4 = (const float4*)hist[s];
                        #pragma unroll
                        for (int c = 0; c < 7; ++c) {
                            const float4 hv = h4[c];
                            const float* wc = &WdT[col * 57 + 4 * c];
                            acc = fmaf(hv.x, wc[0], acc);
                            acc = fmaf(hv.y, wc[1], acc);
                            acc = fmaf(hv.z, wc[2], acc);
                            acc = fmaf(hv.w, wc[3], acc);
                            if (j == 0) {
                                const float* w9 = &WdT[9 * 57 + 4 * c];
                                acc9 = fmaf(hv.x, w9[0], acc9);
                                acc9 = fmaf(hv.y, w9[1], acc9);
                                acc9 = fmaf(hv.z, w9[2], acc9);
                                acc9 = fmaf(hv.w, w9[3], acc9);
                            }
                        }
                    } else if (p == 1) {
                        // ---- A2: matvec k = 28..49 + softplus + publish ----
                        const float4* h4 = (const float4*)hist[s];
                        #pragma unroll
                        for (int c = 7; c < 13; ++c) {
                            const float4 hv = h4[c];
                            const float* wc = &WdT[col * 57 + 4 * c];
                            const float  he[4] = {hv.x, hv.y, hv.z, hv.w};
                            #pragma unroll
                            for (int e = 0; e < 4; ++e) {
                                const int k = 4 * c + e;
                                if (k < H_DIM) {
                                    acc = fmaf(he[e], wc[e], acc);
                                    if (j == 0)
                                        acc9 = fmaf(he[e], WdT[9 * 57 + k], acc9);
                                }
                            }
                        }
                        if (j < 55) {
                            float v = acc;
                            if (isd) v = (v > 20.0f) ? v : log1pf(__expf(v));
                            Lp[dwi][j] = v;
                        } else {
                            mrow[dwi][j - 55] = acc;
                        }
                        if (j == 0) mrow[dwi][9] = acc9;
                    } else if (p == 2) {
                        // ---- B1: Sigma + mu writes + forward substitution ----
                        if (j < 55) {
                            float sgm = 0.0f;
                            for (int k = 0; k <= b; ++k)
                                sgm = fmaf(Lp[dwi][a * (a + 1) / 2 + k],
                                           Lp[dwi][b * (b + 1) / 2 + k], sgm);
                            omir[s * 100 + a * 10 + b] = sgm;
                            omir[s * 100 + b * 10 + a] = sgm;
                        } else {
                            omir[10000 + s * 10 + (j - 55)] = acc;
                        }
                        if (j == 0) omir[10000 + s * 10 + 9] = acc9;

                        // Lp -> registers (static indices only), then fsub.
                        float lp[56];
                        const float4* l4 = (const float4*)Lp[dwi];
                        #pragma unroll
                        for (int c = 0; c < 14; ++c) {
                            const float4 v = l4[c];
                            lp[4 * c + 0] = v.x; lp[4 * c + 1] = v.y;
                            lp[4 * c + 2] = v.z; lp[4 * c + 3] = v.w;
                        }
                        if (j < Z_DIM) {
                            const int k = j;
                            float dinv[Z_DIM];
                            #pragma unroll
                            for (int i = 0; i < Z_DIM; ++i)
                                dinv[i] = 1.0f / lp[i * (i + 1) / 2 + i];
                            float cl[Z_DIM];
                            #pragma unroll
                            for (int i = 0; i < Z_DIM; ++i) cl[i] = 0.0f;
                            #pragma unroll
                            for (int i = 0; i < Z_DIM; ++i) {
                                float sfs = 0.0f;
                                #pragma unroll
                                for (int m = 0; m < i; ++m)
                                    sfs = fmaf(lp[i * (i + 1) / 2 + m], cl[m], sfs);
                                if (i >= k) cl[i] = (i == k) ? dinv[i] : -sfs * dinv[i];
                            }
                            #pragma unroll
                            for (int i = 0; i < Z_DIM; ++i)
                                if (i >= k) Li[dwi][i * (i + 1) / 2 + k] = cl[i];
                        }
                    } else {
                        // ---- B2: J = Linv^T Linv ; h_nat = J mu ----
                        if (j < 55) {
                            float sj = 0.0f;
                            for (int m = a; m < Z_DIM; ++m)
                                sj = fmaf(Li[dwi][m * (m + 1) / 2 + a],
                                          Li[dwi][m * (m + 1) / 2 + b], sj);
                            omir[11000 + s * 100 + a * 10 + b] = sj;
                            omir[11000 + s * 100 + b * 10 + a] = sj;
                            Jsh[dwi][a * 10 + b] = sj;
                            Jsh[dwi][b * 10 + a] = sj;
                        }
                        lds_fence_wave();
                        if (j < Z_DIM) {
                            float sh = 0.0f;
                            #pragma unroll
                            for (int k2 = 0; k2 < Z_DIM; ++k2)
                                sh = fmaf(Jsh[dwi][j * 10 + k2], mrow[dwi][k2], sh);
                            omir[21000 + s * 10 + j] = sh;
                        }
                    }
                }
            }
        }
        __syncthreads();     // unconditional: every wave, every interval
    }

    // ---------------- final dump: LDS mirror -> global (linear f4) ------
    {
        const float4* src = (const float4*)omir;
        float4*       dst = (float4*)out;
        for (int idx = tid; idx < 22000 / 4; idx += NTHREADS)
            dst[idx] = src[idx];
    }
}

extern "C" void kernel_launch(void* const* d_in, const int* in_sizes, int n_in,
                              void* d_out, int out_size, void* d_ws, size_t ws_size,
                              hipStream_t stream) {
    const float* p[15];
    for (int i = 0; i < 15; ++i) p[i] = (const float*)d_in[i];

    gru_fused_kernel<<<dim3(1), dim3(NTHREADS), 0, stream>>>(
        p[0],
        p[1], p[2], p[3], p[4],
        p[5], p[6], p[7], p[8],
        p[9], p[10], p[11], p[12],
        p[13], p[14],
        (float*)d_out);
}

// Round 8
// 124.367 us; speedup vs baseline: 1.8162x; 1.8162x over previous
//
#include <hip/hip_runtime.h>
#include <hip/hip_bf16.h>
#include <math.h>

// Problem constants
#define T_STEPS 100
#define H_DIM   50
#define Z_DIM   10
#define OUT_DIM 65   // Z + Z*(Z+1)/2 = 10 + 55
#define KP      25   // f16 pairs per gate column

typedef _Float16 half2v __attribute__((ext_vector_type(2)));

// ---- cross-lane primitives ----
__device__ __forceinline__ float bcast_lane(float v, int lane) {
    return __uint_as_float(__builtin_amdgcn_readlane(__float_as_uint(v), lane));
}
__device__ __forceinline__ unsigned readlane_u(unsigned v, int lane) {
    return (unsigned)__builtin_amdgcn_readlane((int)v, lane);
}
// DPP cross-lane fetch (VALU speed). bound_ctrl=1 -> invalid source reads 0.
template<int CTRL>
__device__ __forceinline__ float dpp_mov(float x) {
    return __uint_as_float((unsigned)__builtin_amdgcn_update_dpp(
        0, (int)__float_as_uint(x), CTRL, 0xF, 0xF, true));
}
#define DPP_ROW_SHL1 0x101   // lane i <- lane i+1
#define DPP_SHR1     0x111
#define DPP_SHR2     0x112
#define DPP_SHR4     0x114
#define DPP_SHR8     0x118
#define DPP_BCAST15  0x142
#define DPP_BCAST31  0x143

// ---- packed f16 helpers ----
__device__ __forceinline__ unsigned pack_h2(float lo, float hi) {
#if __has_builtin(__builtin_amdgcn_cvt_pkrtz)
    return __builtin_bit_cast(unsigned, __builtin_amdgcn_cvt_pkrtz(lo, hi));
#else
    half2v p; p.x = (_Float16)lo; p.y = (_Float16)hi;
    return __builtin_bit_cast(unsigned, p);
#endif
}
__device__ __forceinline__ float fdot2h(unsigned a, unsigned b, float c) {
#if __has_builtin(__builtin_amdgcn_fdot2)
    return __builtin_amdgcn_fdot2(__builtin_bit_cast(half2v, a),
                                  __builtin_bit_cast(half2v, b), c, false);
#else
    const half2v x = __builtin_bit_cast(half2v, a);
    const half2v y = __builtin_bit_cast(half2v, b);
    return fmaf((float)x.x, (float)y.x, fmaf((float)x.y, (float)y.y, c));
#endif
}

// ---- fast math ----
__device__ __forceinline__ float fast_rcp(float x) { return __builtin_amdgcn_rcpf(x); }
__device__ __forceinline__ float fast_rsq(float x) { return __builtin_amdgcn_rsqf(x); }
__device__ __forceinline__ float fast_sigmoid(float x) {
    return fast_rcp(1.0f + __expf(-x));
}
__device__ __forceinline__ float fast_tanh(float y) {
    return 1.0f - 2.0f * fast_rcp(__expf(2.0f * y) + 1.0f);
}

// =====================================================================
// Kernel 1: serial recurrence, 3 waves (one gate per wave).
// Round-5 configuration -- the measured optimum (39.5 us):
//  - one gate per wave (25 dot2/wave), one barrier per step
//  - all 25 v_readlane broadcasts hoisted into pinned SGPRs before the
//    dot2 chains (kills the VALU-writes-SGPR -> VALU-reads-SGPR
//    wait-state hazard; the single biggest win of the session)
//  - LDS h-history + end dump: zero global ops in the t-loop
// =====================================================================
__global__ __launch_bounds__(192, 1)
void gru_recur_kernel(
    const float* __restrict__ carry_init,
    const float* __restrict__ W_hr, const float* __restrict__ b_hr,
    const float* __restrict__ s_r,  const float* __restrict__ o_r,
    const float* __restrict__ W_hz, const float* __restrict__ b_hz,
    const float* __restrict__ s_z,  const float* __restrict__ o_z,
    const float* __restrict__ W_hn, const float* __restrict__ b_hn,
    const float* __restrict__ s_n,  const float* __restrict__ o_n,
    float* __restrict__ ws_h)
{
    const int  tid   = threadIdx.x;
    const int  wave  = tid >> 6;          // 0:r  1:z  2:n
    const int  j     = tid & 63;
    const bool valid = (j < H_DIM);
    const int  jc    = valid ? j : 0;

    // Per-wave gate parameter selection (wave-uniform branches).
    const float* Wg = (wave == 0) ? W_hr : (wave == 1) ? W_hz : W_hn;
    const float* bg = (wave == 0) ? b_hr : (wave == 1) ? b_hz : b_hn;
    const float* sg = (wave == 0) ? s_r  : (wave == 1) ? s_z  : s_n;
    const float* og = (wave == 0) ? o_r  : (wave == 1) ? o_z  : o_n;

    // Lane j: column j of this wave's gate W, packed f16 pairs over K.
    // Invalid lanes get zero weights/bias -> activations exactly 0 ->
    // LN stats need no masking.
    unsigned w[KP];
    #pragma unroll
    for (int k = 0; k < KP; ++k) {
        const int i0 = 2 * k, i1 = 2 * k + 1;
        w[k] = pack_h2(valid ? Wg[i0 * H_DIM + j] : 0.0f,
                       valid ? Wg[i1 * H_DIM + j] : 0.0f);
    }
    // Pin: forbid rematerializing the loads/converts inside the t-loop.
    #pragma unroll
    for (int k = 0; k < KP; ++k) asm volatile("" : "+v"(w[k]));

    const float bj = valid ? bg[jc] : 0.0f;
    const float sc = sg[jc];
    const float of = og[jc];

    __shared__ float gbuf[2][3][64];                    // double-buffered gate exchange
    __shared__ __align__(16) float hist[T_STEPS][64];   // h history, dumped at end

    float h = valid ? carry_init[jc] : 0.0f;
    const float invH = 1.0f / (float)H_DIM;

    // Packed broadcast source: even lane 2k holds (h_2k, h_{2k+1}).
    // row_shl:1 (lane i <- i+1) stays in-row since 2k is even.
    float    hsl = dpp_mov<DPP_ROW_SHL1>(h);
    unsigned hpk = pack_h2(h, hsl);

    #pragma unroll 1
    for (int t = 0; t < T_STEPS; ++t) {
        // ---- hoisted broadcasts: 25 independent readlanes -> SGPRs ----
        // Issued back-to-back so they pipeline; by the time the first
        // dot2 consumes hs[0], its SGPR write is long retired.
        unsigned hs[KP];
        #pragma unroll
        for (int k = 0; k < KP; ++k) hs[k] = readlane_u(hpk, 2 * k);
        #pragma unroll
        for (int k = 0; k < KP; ++k) asm volatile("" : "+s"(hs[k]));

        // ---- this wave's matvec via dot2: a_j = b_j + sum_i h_i*W[i][j] ----
        float a0 = bj, a1 = 0.0f;
        #pragma unroll
        for (int k = 0; k < KP; k += 2) {
            a0 = fdot2h(hs[k], w[k], a0);
            if (k + 1 < KP) a1 = fdot2h(hs[k + 1], w[k + 1], a1);
        }
        const float a = a0 + a1;

        // ---- LN stats: 2 quantities, DPP tree ----
        float m = a, q = a * a;
        #define STAGE(C) m += dpp_mov<C>(m); q += dpp_mov<C>(q);
        STAGE(DPP_SHR1) STAGE(DPP_SHR2) STAGE(DPP_SHR4)
        STAGE(DPP_SHR8) STAGE(DPP_BCAST15) STAGE(DPP_BCAST31)
        #undef STAGE
        m = bcast_lane(m, 63); q = bcast_lane(q, 63);

        // ---- layernorm + this gate's activation ----
        const float mu  = m * invH;
        const float var = fmaxf(q * invH - mu * mu, 0.0f);
        const float g   = (a - mu) * fast_rsq(var + 1e-6f) * sc + of;
        const float val = (wave == 2) ? g : fast_sigmoid(g);   // n-gate: pre-tanh

        gbuf[t & 1][wave][j] = val;
        __syncthreads();   // one barrier/step; double buffer makes it sufficient

        // ---- combine (redundant in all 3 waves) ----
        const float r  = gbuf[t & 1][0][j];
        const float z  = gbuf[t & 1][1][j];
        const float gn = gbuf[t & 1][2][j];
        const float n  = fast_tanh(r * gn);
        h = n + z * (h - n);              // (1-z)*n + z*h

        if (wave == 0) hist[t][j] = h;

        // repack broadcast source for next step
        hsl = dpp_mov<DPP_ROW_SHL1>(h);
        hpk = pack_h2(h, hsl);
    }

    __syncthreads();
    // Vectorized LDS -> global dump of the whole history.
    {
        float4*       dst = (float4*)ws_h;
        const float4* src = (const float4*)hist;
        for (int i = tid; i < T_STEPS * 16; i += 192)
            dst[i] = src[i];
    }
}

// =====================================================================
// Kernel 2: dense projection + nat transform. One block per timestep,
// parallel across CUs. (Verbatim round-1 version.)
// =====================================================================
__global__ __launch_bounds__(128)
void dense_nat_kernel(
    const float* __restrict__ W_dense, const float* __restrict__ b_dense,
    const float* __restrict__ ws_h, float* __restrict__ out)
{
    const int t   = blockIdx.x;
    const int tid = threadIdx.x;

    __shared__ float hloc[H_DIM];
    __shared__ float dl  [OUT_DIM];
    __shared__ float Lp  [55];
    __shared__ float Li  [55];
    __shared__ float Jsh [100];

    if (tid < H_DIM) hloc[tid] = ws_h[t * 64 + tid];
    __syncthreads();

    if (tid < OUT_DIM) {
        float acc = b_dense[tid];
        #pragma unroll
        for (int i = 0; i < H_DIM; ++i)
            acc = fmaf(hloc[i], W_dense[i * OUT_DIM + tid], acc);
        dl[tid] = acc;
    }
    __syncthreads();

    // Lp = packed lower-tri L with softplus applied to diagonal entries.
    if (tid < 55) {
        float v = dl[Z_DIM + tid];
        const bool isd = (tid==0)|(tid==2)|(tid==5)|(tid==9)|(tid==14)|
                         (tid==20)|(tid==27)|(tid==35)|(tid==44)|(tid==54);
        if (isd) v = (v > 20.0f) ? v : log1pf(__expf(v));
        Lp[tid] = v;
    }
    __syncthreads();

    float* outSigma = out;           // [100][10][10]
    float* outMu    = out + 10000;   // [100][10]
    float* outJ     = out + 11000;   // [100][10][10]
    float* outHnat  = out + 21000;   // [100][10]

    // Map flat tri index -> (a,b), a >= b
    int a = 0;
    {
        #pragma unroll
        for (int x = 1; x < Z_DIM; ++x)
            if (tid >= x * (x + 1) / 2) a = x;
    }
    const int b = tid - a * (a + 1) / 2;

    // Sigma = L @ L^T (one entry per thread)
    if (tid < 55) {
        float s = 0.0f;
        for (int k = 0; k <= b; ++k)
            s = fmaf(Lp[a * (a + 1) / 2 + k], Lp[b * (b + 1) / 2 + k], s);
        outSigma[t * 100 + a * 10 + b] = s;
        outSigma[t * 100 + b * 10 + a] = s;
    }
    if (tid >= 64 && tid < 64 + Z_DIM) outMu[t * 10 + (tid - 64)] = dl[tid - 64];
    __syncthreads();

    // Linv by forward substitution: thread k owns column k in registers.
    if (tid < Z_DIM) {
        const int k = tid;
        float dinv[Z_DIM];
        #pragma unroll
        for (int i = 0; i < Z_DIM; ++i)
            dinv[i] = 1.0f / Lp[i * (i + 1) / 2 + i];
        float col[Z_DIM];
        #pragma unroll
        for (int i = 0; i < Z_DIM; ++i) col[i] = 0.0f;
        #pragma unroll
        for (int i = 0; i < Z_DIM; ++i) {
            float s = 0.0f;
            #pragma unroll
            for (int m = 0; m < i; ++m)
                s = fmaf(Lp[i * (i + 1) / 2 + m], col[m], s);
            if (i >= k) col[i] = (i == k) ? dinv[i] : -s * dinv[i];
        }
        #pragma unroll
        for (int i = 0; i < Z_DIM; ++i)
            if (i >= k) Li[i * (i + 1) / 2 + k] = col[i];
    }
    __syncthreads();

    // J = Linv^T @ Linv (one entry per thread)
    if (tid < 55) {
        float s = 0.0f;
        for (int m = a; m < Z_DIM; ++m)
            s = fmaf(Li[m * (m + 1) / 2 + a], Li[m * (m + 1) / 2 + b], s);
        outJ[t * 100 + a * 10 + b] = s;
        outJ[t * 100 + b * 10 + a] = s;
        Jsh[a * 10 + b] = s;
        Jsh[b * 10 + a] = s;
    }
    __syncthreads();

    // h_nat = J @ mu
    if (tid < Z_DIM) {
        float s = 0.0f;
        #pragma unroll
        for (int k = 0; k < Z_DIM; ++k)
            s = fmaf(Jsh[tid * 10 + k], dl[k], s);
        outHnat[t * 10 + tid] = s;
    }
}

extern "C" void kernel_launch(void* const* d_in, const int* in_sizes, int n_in,
                              void* d_out, int out_size, void* d_ws, size_t ws_size,
                              hipStream_t stream) {
    const float* p[15];
    for (int i = 0; i < 15; ++i) p[i] = (const float*)d_in[i];
    float* ws_h = (float*)d_ws;   // [T_STEPS][64] f32 = 25600 B

    gru_recur_kernel<<<dim3(1), dim3(192), 0, stream>>>(
        p[0],
        p[1], p[2], p[3], p[4],
        p[5], p[6], p[7], p[8],
        p[9], p[10], p[11], p[12],
        ws_h);

    dense_nat_kernel<<<dim3(T_STEPS), dim3(128), 0, stream>>>(
        p[13], p[14], ws_h, (float*)d_out);
}